// Round 1
// baseline (3111.352 us; speedup 1.0000x reference)
//
#include <hip/hip_runtime.h>
#include <cstddef>

#define B 32
#define T_ENC 512
#define T_DEC 32
#define E 256
#define VOCAB 32000
#define SOS 1

// ---------------- workspace layout (float offsets) ----------------
static const size_t OFF_ENCWM = 0;                                  // B*T_ENC*E
static const size_t OFF_ENCWC = OFF_ENCWM + (size_t)B * T_ENC * E;  // B*T_ENC*E
static const size_t OFF_WEFFM = OFF_ENCWC + (size_t)B * T_ENC * E;  // E
static const size_t OFF_WEFFC = OFF_WEFFM + E;                      // E
static const size_t OFF_H     = OFF_WEFFC + E;                      // B*E
static const size_t OFF_HVM   = OFF_H + (size_t)B * E;              // B*E
static const size_t OFF_HVC   = OFF_HVM + (size_t)B * E;            // B*E
static const size_t OFF_P     = OFF_HVC + (size_t)B * E;            // B*T_ENC
static const size_t OFF_EC    = OFF_P + (size_t)B * T_ENC;          // B*T_ENC
static const size_t OFF_ALPHA = OFF_EC + (size_t)B * T_ENC;         // B*T_ENC
static const size_t OFF_ATTN  = OFF_ALPHA + (size_t)B * T_ENC;      // B*T_DEC*E
// total ~8.72M floats ~= 34.9 MB

// ---------------- w_eff = (g/||vv||)*vv ----------------
__global__ __launch_bounds__(256) void weff_kernel(
    const float* __restrict__ vvm, const float* __restrict__ gm, float* __restrict__ w_effm,
    const float* __restrict__ vvc, const float* __restrict__ gc, float* __restrict__ w_effc)
{
  const float* vv = blockIdx.x ? vvc : vvm;
  const float* g  = blockIdx.x ? gc  : gm;
  float* out      = blockIdx.x ? w_effc : w_effm;
  __shared__ float red[256];
  int tid = threadIdx.x;
  float v = vv[tid];
  red[tid] = v * v;
  __syncthreads();
  for (int off = 128; off > 0; off >>= 1) {
    if (tid < off) red[tid] += red[tid + off];
    __syncthreads();
  }
  float norm = sqrtf(red[0]);
  out[tid] = (g[0] / norm) * v;
}

// ---------------- init alpha0 + copy h0 ----------------
__global__ __launch_bounds__(256) void init_kernel(
    float* __restrict__ alpha, float* __restrict__ h_g, const float* __restrict__ h0)
{
  int i = blockIdx.x * 256 + threadIdx.x;   // grid 64 -> 16384 threads
  alpha[i] = ((i & (T_ENC - 1)) == 0) ? 1.0f : 0.0f;
  if (i < B * E) h_g[i] = h0[i];
}

// ---------------- Y[r,n] = bias[n] + sum_k A[r,k]*W[n,k] ----------------
// 64x64 tile, 256 threads, 4x4 per thread, LDS transposed (As[k][m], Ws[k][n])
__global__ __launch_bounds__(256) void gemm_xwt(
    const float* __restrict__ A, const float* __restrict__ W,
    const float* __restrict__ bias, float* __restrict__ Y,
    int M, int N, int K)
{
  __shared__ float As[64][68];  // pad 68: keeps 16B alignment for b128 reads, breaks bank conflicts
  __shared__ float Ws[64][68];
  const int tid = threadIdx.x;
  const int tx = tid & 15, ty = tid >> 4;
  const int row0 = blockIdx.y * 64, col0 = blockIdx.x * 64;
  float acc[4][4];
#pragma unroll
  for (int i = 0; i < 4; i++)
#pragma unroll
    for (int j = 0; j < 4; j++) acc[i][j] = 0.f;

  for (int k0 = 0; k0 < K; k0 += 64) {
#pragma unroll
    for (int s = 0; s < 4; s++) {
      int i = (s << 4) + ty;
      int j = tx << 2;
      float4 av = *(const float4*)(A + (size_t)(row0 + i) * K + k0 + j);
      As[j][i] = av.x; As[j + 1][i] = av.y; As[j + 2][i] = av.z; As[j + 3][i] = av.w;
      float4 wv = *(const float4*)(W + (size_t)(col0 + i) * K + k0 + j);
      Ws[j][i] = wv.x; Ws[j + 1][i] = wv.y; Ws[j + 2][i] = wv.z; Ws[j + 3][i] = wv.w;
    }
    __syncthreads();
#pragma unroll
    for (int kk = 0; kk < 64; kk++) {
      const float4 af = *(const float4*)&As[kk][ty << 2];
      const float4 bf = *(const float4*)&Ws[kk][tx << 2];
      acc[0][0] += af.x * bf.x; acc[0][1] += af.x * bf.y; acc[0][2] += af.x * bf.z; acc[0][3] += af.x * bf.w;
      acc[1][0] += af.y * bf.x; acc[1][1] += af.y * bf.y; acc[1][2] += af.y * bf.z; acc[1][3] += af.y * bf.w;
      acc[2][0] += af.z * bf.x; acc[2][1] += af.z * bf.y; acc[2][2] += af.z * bf.z; acc[2][3] += af.z * bf.w;
      acc[3][0] += af.w * bf.x; acc[3][1] += af.w * bf.y; acc[3][2] += af.w * bf.z; acc[3][3] += af.w * bf.w;
    }
    __syncthreads();
  }
  const float4 bv = *(const float4*)(bias + col0 + (tx << 2));
#pragma unroll
  for (int i = 0; i < 4; i++) {
    float4 o;
    o.x = acc[i][0] + bv.x; o.y = acc[i][1] + bv.y;
    o.z = acc[i][2] + bv.z; o.w = acc[i][3] + bv.w;
    *(float4*)(Y + (size_t)(row0 + (ty << 2) + i) * N + col0 + (tx << 2)) = o;
  }
}

// ---------------- RNN cell + h@Vm.T, h@Vc.T ; one block per b ----------------
__global__ __launch_bounds__(256) void rnn_kernel(
    const int* __restrict__ dec_in, const float* __restrict__ emb,
    const float* __restrict__ W_ih, const float* __restrict__ b_ih,
    const float* __restrict__ W_hh, const float* __restrict__ b_hh,
    const float* __restrict__ Vm, const float* __restrict__ Vc,
    float* __restrict__ h_g, float* __restrict__ hVm, float* __restrict__ hVc,
    int step)
{
  __shared__ float xs[256], hs[256], hn[256];
  const int b = blockIdx.x, tid = threadIdx.x;
  const int tok = (step == 0) ? SOS : dec_in[b * T_DEC + step - 1];
  xs[tid] = emb[(size_t)tok * E + tid];
  hs[tid] = h_g[(size_t)b * E + tid];
  __syncthreads();
  float acc = b_ih[tid] + b_hh[tid];
  const float* wi = W_ih + (size_t)tid * E;
  const float* wh = W_hh + (size_t)tid * E;
#pragma unroll 4
  for (int e = 0; e < 256; e += 4) {
    float4 a = *(const float4*)(wi + e);
    float4 c = *(const float4*)(wh + e);
    acc += xs[e] * a.x + xs[e + 1] * a.y + xs[e + 2] * a.z + xs[e + 3] * a.w
         + hs[e] * c.x + hs[e + 1] * c.y + hs[e + 2] * c.z + hs[e + 3] * c.w;
  }
  float hv = tanhf(acc);
  hn[tid] = hv;
  h_g[(size_t)b * E + tid] = hv;
  __syncthreads();
  float am = 0.f, acv = 0.f;
  const float* vm = Vm + (size_t)tid * E;
  const float* vc = Vc + (size_t)tid * E;
#pragma unroll 4
  for (int e = 0; e < 256; e += 4) {
    float4 a = *(const float4*)(vm + e);
    float4 c = *(const float4*)(vc + e);
    am  += hn[e] * a.x + hn[e + 1] * a.y + hn[e + 2] * a.z + hn[e + 3] * a.w;
    acv += hn[e] * c.x + hn[e + 1] * c.y + hn[e + 2] * c.z + hn[e + 3] * c.w;
  }
  hVm[(size_t)b * E + tid] = am;
  hVc[(size_t)b * E + tid] = acv;
}

// ---------------- energies -> p (with noise+sigmoid) and e_c ; one wave per (b,t) ----------------
__global__ __launch_bounds__(256) void energy_kernel(
    const float* __restrict__ encWm, const float* __restrict__ encWc,
    const float* __restrict__ hVm, const float* __restrict__ hVc,
    const float* __restrict__ w_effm, const float* __restrict__ w_effc,
    const float* __restrict__ vbm, const float* __restrict__ rmp,
    const float* __restrict__ vbc, const float* __restrict__ rcp,
    const float* __restrict__ noise, float* __restrict__ p_buf,
    float* __restrict__ ec_buf, int step)
{
  const int wave = threadIdx.x >> 6, lane = threadIdx.x & 63;
  const int idx = blockIdx.x * 4 + wave;       // idx = b*T_ENC + t
  const int b = idx >> 9;
  const int a0 = lane << 2;
  float4 em  = *(const float4*)(encWm + (size_t)idx * E + a0);
  float4 ecv = *(const float4*)(encWc + (size_t)idx * E + a0);
  float4 hm  = *(const float4*)(hVm + (size_t)b * E + a0);
  float4 hc  = *(const float4*)(hVc + (size_t)b * E + a0);
  float4 wm  = *(const float4*)(w_effm + a0);
  float4 wc  = *(const float4*)(w_effc + a0);
  float sm = wm.x * tanhf(em.x + hm.x) + wm.y * tanhf(em.y + hm.y)
           + wm.z * tanhf(em.z + hm.z) + wm.w * tanhf(em.w + hm.w);
  float sc = wc.x * tanhf(ecv.x + hc.x) + wc.y * tanhf(ecv.y + hc.y)
           + wc.z * tanhf(ecv.z + hc.z) + wc.w * tanhf(ecv.w + hc.w);
#pragma unroll
  for (int off = 32; off > 0; off >>= 1) {
    sm += __shfl_down(sm, off, 64);
    sc += __shfl_down(sc, off, 64);
  }
  if (lane == 0) {
    float e_m = sm + vbm[0] + rmp[0];
    float z = e_m + noise[(size_t)step * (B * T_ENC) + idx];
    p_buf[idx] = 1.0f / (1.0f + expf(-z));
    ec_buf[idx] = sc + vbc[0] + rcp[0];
  }
}

// ---------------- inclusive Hillis-Steele scan over 512 (512 threads) ----------------
__device__ __forceinline__ float scan512(float v, float* a, float* b, int tid)
{
  __syncthreads();            // protect reuse of scratch arrays
  a[tid] = v;
  __syncthreads();
  float* src = a; float* dst = b;
#pragma unroll
  for (int off = 1; off < 512; off <<= 1) {
    float x = src[tid];
    if (tid >= off) x += src[tid - off];
    dst[tid] = x;
    __syncthreads();
    float* t = src; src = dst; dst = t;
  }
  return src[tid];
}

// ---------------- alpha scan + chunkwise beta + context + combine(attn) ; one block per b ----------------
__global__ __launch_bounds__(512) void alpha_kernel(
    const float* __restrict__ p_buf, const float* __restrict__ ec_buf,
    float* __restrict__ alpha_g, const float* __restrict__ enc,
    const float* __restrict__ h_g, const float* __restrict__ W_comb,
    float* __restrict__ attn_ws, int step)
{
  __shared__ float sa[512], sb[512], arr[512], c2S[512], betaS[512], cs[512];
  const int b = blockIdx.x, tid = threadIdx.x;
  const size_t base = (size_t)b * T_ENC + tid;
  float p = p_buf[base];
  float ec = ec_buf[base];
  float aprev = alpha_g[base];

  // exclusive safe cumprod of (1-p): cp = exp(shift(cumsum(log(clip(1-p)))))
  float lg = logf(fminf(fmaxf(1.0f - p, 1e-10f), 1.0f));
  float incl = scan512(lg, sa, sb, tid);
  arr[tid] = incl;
  __syncthreads();
  float excl = (tid == 0) ? 0.0f : arr[tid - 1];
  float cp = expf(excl);

  // alpha = p * cp * cumsum(alpha_prev / clip(cp))
  float ao = aprev / fminf(fmaxf(cp, 1e-10f), 1.0f);
  float s2 = scan512(ao, sa, sb, tid);
  float alpha_new = p * cp * s2;
  alpha_g[base] = alpha_new;

  // block max of e_c
  __syncthreads();
  sa[tid] = ec;
  __syncthreads();
  for (int off = 256; off >= 1; off >>= 1) {
    if (tid < off) sa[tid] = fmaxf(sa[tid], sa[tid + off]);
    __syncthreads();
  }
  float mx = sa[0];
  float eu = expf(ec - mx);

  // denom = clip(moving_sum(eu, back=7, fwd=0)) ; window sum via cumsum diff
  float c1 = scan512(eu, sa, sb, tid);
  arr[tid] = c1;
  __syncthreads();
  float denom = c1 - ((tid >= 8) ? arr[tid - 8] : 0.0f);
  denom = fmaxf(denom, 1e-10f);

  // beta = eu * moving_sum(alpha/denom, back=0, fwd=7)
  float r = alpha_new / denom;
  float c2 = scan512(r, sa, sb, tid);
  c2S[tid] = c2;
  __syncthreads();
  int hi = (tid + 7 < 511) ? (tid + 7) : 511;
  float ms2 = c2S[hi] - ((tid > 0) ? c2S[tid - 1] : 0.0f);
  betaS[tid] = eu * ms2;
  __syncthreads();

  // context[e] = sum_t beta[t] * enc[b,t,e]  (t split across two halves of the block)
  const int e = tid & 255, half = tid >> 8;
  const float* ep = enc + ((size_t)b * T_ENC + (half << 8)) * E + e;
  float ctx = 0.f;
#pragma unroll 4
  for (int t = 0; t < 256; t++)
    ctx += betaS[(half << 8) + t] * ep[(size_t)t * E];
  sa[tid] = ctx;
  __syncthreads();
  if (half == 0) cs[e] = sa[e] + sa[e + 256];     // cs[0:256] = context
  else           cs[256 + e] = h_g[(size_t)b * E + e]; // cs[256:512] = h
  __syncthreads();

  // attn[d] = tanh( [context,h] . W_comb[d,:] ) ; each output d computed by 2 threads (halves of k)
  const float* wr = W_comb + (size_t)e * (2 * E) + (half << 8);
  float acb = 0.f;
#pragma unroll 4
  for (int e2 = 0; e2 < 256; e2 += 4) {
    float4 w = *(const float4*)(wr + e2);
    acb += cs[(half << 8) + e2] * w.x + cs[(half << 8) + e2 + 1] * w.y
         + cs[(half << 8) + e2 + 2] * w.z + cs[(half << 8) + e2 + 3] * w.w;
  }
  sb[tid] = acb;
  __syncthreads();
  if (tid < 256)
    attn_ws[((size_t)b * T_DEC + step) * E + tid] = tanhf(sb[tid] + sb[tid + 256]);
}

// ---------------- launch ----------------
extern "C" void kernel_launch(void* const* d_in, const int* in_sizes, int n_in,
                              void* d_out, int out_size, void* d_ws, size_t ws_size,
                              hipStream_t stream)
{
  (void)in_sizes; (void)n_in; (void)out_size; (void)ws_size;
  const float* enc    = (const float*)d_in[0];
  const int*   dec    = (const int*)d_in[1];
  const float* h0     = (const float*)d_in[2];
  const float* noise  = (const float*)d_in[3];
  const float* emb    = (const float*)d_in[4];
  const float* W_ih   = (const float*)d_in[5];
  const float* b_ih   = (const float*)d_in[6];
  const float* W_hh   = (const float*)d_in[7];
  const float* b_hh   = (const float*)d_in[8];
  const float* Wm     = (const float*)d_in[9];
  const float* Vm     = (const float*)d_in[10];
  const float* bm     = (const float*)d_in[11];
  const float* vvm    = (const float*)d_in[12];
  const float* gm     = (const float*)d_in[13];
  const float* vbm    = (const float*)d_in[14];
  const float* rmp    = (const float*)d_in[15];
  const float* Wc     = (const float*)d_in[16];
  const float* Vc     = (const float*)d_in[17];
  const float* bc     = (const float*)d_in[18];
  const float* vvc    = (const float*)d_in[19];
  const float* gc     = (const float*)d_in[20];
  const float* vbc    = (const float*)d_in[21];
  const float* rcp    = (const float*)d_in[22];
  const float* W_comb = (const float*)d_in[23];
  const float* W_proj = (const float*)d_in[24];
  const float* b_proj = (const float*)d_in[25];

  float* ws = (float*)d_ws;
  float* encWm  = ws + OFF_ENCWM;
  float* encWc  = ws + OFF_ENCWC;
  float* w_effm = ws + OFF_WEFFM;
  float* w_effc = ws + OFF_WEFFC;
  float* h_g    = ws + OFF_H;
  float* hVm    = ws + OFF_HVM;
  float* hVc    = ws + OFF_HVC;
  float* p_buf  = ws + OFF_P;
  float* ec_buf = ws + OFF_EC;
  float* alpha  = ws + OFF_ALPHA;
  float* attn   = ws + OFF_ATTN;
  float* out    = (float*)d_out;

  weff_kernel<<<2, 256, 0, stream>>>(vvm, gm, w_effm, vvc, gc, w_effc);
  init_kernel<<<64, 256, 0, stream>>>(alpha, h_g, h0);
  // step-invariant: encW = enc @ W.T + b  (bias folded here)
  gemm_xwt<<<dim3(E / 64, (B * T_ENC) / 64), 256, 0, stream>>>(enc, Wm, bm, encWm, B * T_ENC, E, E);
  gemm_xwt<<<dim3(E / 64, (B * T_ENC) / 64), 256, 0, stream>>>(enc, Wc, bc, encWc, B * T_ENC, E, E);

  for (int step = 0; step < T_DEC; step++) {
    rnn_kernel<<<B, 256, 0, stream>>>(dec, emb, W_ih, b_ih, W_hh, b_hh, Vm, Vc,
                                      h_g, hVm, hVc, step);
    energy_kernel<<<(B * T_ENC) / 4, 256, 0, stream>>>(encWm, encWc, hVm, hVc,
                                                       w_effm, w_effc, vbm, rmp, vbc, rcp,
                                                       noise, p_buf, ec_buf, step);
    alpha_kernel<<<B, 512, 0, stream>>>(p_buf, ec_buf, alpha, enc, h_g, W_comb, attn, step);
  }

  // deferred projection: logits[b*T_DEC+t, :] = attn @ W_proj.T + b_proj
  gemm_xwt<<<dim3(VOCAB / 64, (B * T_DEC) / 64), 256, 0, stream>>>(attn, W_proj, b_proj, out,
                                                                   B * T_DEC, VOCAB, E);
}